// Round 1
// baseline (2627.425 us; speedup 1.0000x reference)
//
#include <hip/hip_runtime.h>
#include <math.h>

#define BB 32
#define TT1 512
#define TT2 2048
#define HH 80
#define DENC 512
#define NEGV -1000000000.0f
#define SLOPE_ 0.3f
#define TEMP_ 0.0005f

__device__ __forceinline__ float lrelu(float y){ return y >= 0.f ? y : SLOPE_*y; }

// ---------------- conv1: enc_in (B,512,512) -> (B,80,512), k=3 pad=1 ----------------
__global__ __launch_bounds__(256) void conv_k1(
    const float* __restrict__ x, const float* __restrict__ w,
    const float* __restrict__ bias, float* __restrict__ out)
{
  __shared__ float xs[128][66];
  const int b = blockIdx.y;
  const int t0 = blockIdx.x * 64;
  const float* xb = x + (size_t)b*DENC*TT1;
  const int tl = threadIdx.x & 63;
  const int og = __builtin_amdgcn_readfirstlane(threadIdx.x >> 6); // 0..3, 20 outs each
  float acc[20];
  #pragma unroll
  for (int i=0;i<20;i++) acc[i] = 0.f;
  for (int cc = 0; cc < 4; cc++){
    __syncthreads();
    for (int idx = threadIdx.x; idx < 128*66; idx += 256){
      int c = idx / 66, tt = idx - c*66;
      int t = t0 + tt - 1;
      xs[c][tt] = (t >= 0 && t < TT1) ? xb[(size_t)(cc*128 + c)*TT1 + t] : 0.f;
    }
    __syncthreads();
    for (int c = 0; c < 128; c++){
      float x0 = xs[c][tl], x1 = xs[c][tl+1], x2 = xs[c][tl+2];
      const int cg = cc*128 + c;
      #pragma unroll
      for (int oo=0;oo<20;oo++){
        const float* wp = w + (size_t)(og*20+oo)*1536 + cg*3;
        acc[oo] += wp[0]*x0 + wp[1]*x1 + wp[2]*x2;
      }
    }
  }
  #pragma unroll
  for (int oo=0;oo<20;oo++){
    int o = og*20+oo;
    float y = acc[oo] + bias[o];
    out[((size_t)b*HH + o)*TT1 + t0 + tl] = lrelu(y);
  }
}

// ---------------- generic 80->80 conv ----------------
template<int KS, int T, int TTILE, int TPW>
__global__ __launch_bounds__(256) void conv80(
    const float* __restrict__ x, const float* __restrict__ w,
    const float* __restrict__ bias, float* __restrict__ out)
{
  constexpr int PAD = (KS-1)/2;
  constexpr int XW = TTILE + KS - 1;
  __shared__ float xs[80][XW];
  const int b = blockIdx.y;
  const int t0 = blockIdx.x * TTILE;
  const float* xb = x + (size_t)b*80*T;
  for (int idx = threadIdx.x; idx < 80*XW; idx += 256){
    int c = idx / XW, tt = idx - c*XW;
    int t = t0 + tt - PAD;
    xs[c][tt] = (t >= 0 && t < T) ? xb[(size_t)c*T + t] : 0.f;
  }
  __syncthreads();
  const int tl = threadIdx.x & 63;
  const int og = __builtin_amdgcn_readfirstlane(threadIdx.x >> 6);
  const float* wb = w + (size_t)og*20*80*KS;
  float acc[TPW][20];
  #pragma unroll
  for (int i=0;i<TPW;i++)
    #pragma unroll
    for (int j=0;j<20;j++) acc[i][j] = 0.f;
  for (int c=0;c<80;c++){
    float xv[TPW + KS - 1];
    #pragma unroll
    for (int u=0;u<TPW+KS-1;u++) xv[u] = xs[c][tl*TPW + u];
    #pragma unroll
    for (int oo=0;oo<20;oo++){
      const float* wp = wb + (size_t)oo*80*KS + c*KS;
      #pragma unroll
      for (int dt=0; dt<KS; dt++){
        float wv = wp[dt];
        #pragma unroll
        for (int tt=0;tt<TPW;tt++)
          acc[tt][oo] += wv * xv[tt+dt];
      }
    }
  }
  #pragma unroll
  for (int oo=0;oo<20;oo++){
    int o = og*20 + oo;
    float bv = bias[o];
    if (TPW == 2){
      float2 y2;
      y2.x = lrelu(acc[0][oo] + bv);
      y2.y = lrelu(acc[1][oo] + bv);
      *(float2*)&out[((size_t)b*80 + o)*T + t0 + tl*2] = y2;
    } else {
      out[((size_t)b*80 + o)*T + t0 + tl] = lrelu(acc[0][oo] + bv);
    }
  }
}

// ---------------- k2 = sum_c k^2 ----------------
__global__ __launch_bounds__(256) void k2_kernel(const float* __restrict__ k, float* __restrict__ k2){
  int b = blockIdx.x;
  for (int s = threadIdx.x; s < TT1; s += 256){
    float a = 0.f;
    for (int c=0;c<80;c++){
      float v = k[((size_t)b*80 + c)*TT1 + s];
      a += v*v;
    }
    k2[b*TT1 + s] = a;
  }
}

// ---------------- attention: qk, two softmaxes, write out0/out1, zero out2, save lse2 ----------------
__global__ __launch_bounds__(256) void attn_kernel(
    const float* __restrict__ q,    // (B,80,2048)
    const float* __restrict__ k,    // (B,80,512)
    const float* __restrict__ k2g,  // (B,512)
    const float* __restrict__ prior,// (B,512,2048)
    float* __restrict__ out0, float* __restrict__ out1, float* __restrict__ out2,
    float* __restrict__ lse2)       // (B,2048): logsumexp of out0 rows
{
  const int b = blockIdx.y;
  const int t0 = blockIdx.x * 32;
  __shared__ float klds[80][128];
  __shared__ float qlds[80][32];
  __shared__ float q2lds[32];
  const int tid = threadIdx.x;
  const float* qb = q + (size_t)b*80*TT2;
  const float* kb = k + (size_t)b*80*TT1;
  for (int idx = tid; idx < 80*32; idx += 256){
    int c = idx >> 5, tt = idx & 31;
    qlds[c][tt] = qb[(size_t)c*TT2 + t0 + tt];
  }
  __syncthreads();
  if (tid < 32){
    float s = 0.f;
    for (int c = 0; c < 80; c++){ float v = qlds[c][tid]; s += v*v; }
    q2lds[tid] = s;
  }
  const int s_thr = tid & 31;   // 4 s each (per chunk)
  const int t_thr = tid >> 5;   // 4 t each
  float acc[4][16];
  #pragma unroll
  for (int i=0;i<4;i++)
    #pragma unroll
    for (int j=0;j<16;j++) acc[i][j] = 0.f;
  #pragma unroll
  for (int ch = 0; ch < 4; ch++){
    __syncthreads();
    for (int idx = tid; idx < 80*128; idx += 256){
      int c = idx >> 7, ss = idx & 127;
      klds[c][ss] = kb[(size_t)c*TT1 + ch*128 + ss];
    }
    __syncthreads();
    for (int c = 0; c < 80; c++){
      float4 kv = *(const float4*)&klds[c][s_thr<<2];
      float4 qv = *(const float4*)&qlds[c][t_thr<<2];
      float kx[4] = {kv.x,kv.y,kv.z,kv.w};
      float qx[4] = {qv.x,qv.y,qv.z,qv.w};
      #pragma unroll
      for (int tt=0;tt<4;tt++)
        #pragma unroll
        for (int jj=0;jj<4;jj++)
          acc[tt][ch*4+jj] += qx[tt]*kx[jj];
    }
  }
  // k2 for this thread's 16 s columns
  float k2l[16];
  #pragma unroll
  for (int ch=0; ch<4; ch++){
    float4 kk = *(const float4*)&k2g[(size_t)b*TT1 + ch*128 + (s_thr<<2)];
    k2l[ch*4+0]=kk.x; k2l[ch*4+1]=kk.y; k2l[ch*4+2]=kk.z; k2l[ch*4+3]=kk.w;
  }
  #pragma unroll
  for (int tt=0; tt<4; tt++){
    const int t = t0 + (t_thr<<2) + tt;
    const float q2t = q2lds[(t_thr<<2)+tt];
    float v[16];
    #pragma unroll
    for (int u=0;u<16;u++) v[u] = -TEMP_ * (q2t + k2l[u] - 2.f*acc[tt][u]);
    // prior loads (early issue)
    float pv[16];
    #pragma unroll
    for (int ch=0; ch<4; ch++)
      #pragma unroll
      for (int jj=0;jj<4;jj++){
        int s = ch*128 + (s_thr<<2) + jj;
        pv[ch*4+jj] = prior[((size_t)b*TT1 + s)*TT2 + t];
      }
    // pass 1: log_softmax over 512 (32-lane group reduce)
    float m = v[0];
    #pragma unroll
    for (int u=1;u<16;u++) m = fmaxf(m, v[u]);
    m = fmaxf(m, __shfl_xor(m, 1));  m = fmaxf(m, __shfl_xor(m, 2));
    m = fmaxf(m, __shfl_xor(m, 4));  m = fmaxf(m, __shfl_xor(m, 8));
    m = fmaxf(m, __shfl_xor(m, 16));
    float l = 0.f;
    #pragma unroll
    for (int u=0;u<16;u++) l += expf(v[u]-m);
    l += __shfl_xor(l, 1); l += __shfl_xor(l, 2); l += __shfl_xor(l, 4);
    l += __shfl_xor(l, 8); l += __shfl_xor(l, 16);
    float lse = m + logf(l);
    #pragma unroll
    for (int u=0;u<16;u++) v[u] = v[u] - lse + logf(pv[u] + 1e-8f);
    size_t ob = ((size_t)b*TT2 + t)*TT1 + (s_thr<<2);
    #pragma unroll
    for (int ch=0; ch<4; ch++){
      float4 w4 = {v[ch*4], v[ch*4+1], v[ch*4+2], v[ch*4+3]};
      *(float4*)&out0[ob + ch*128] = w4;
    }
    // pass 2: softmax of v
    float m2 = v[0];
    #pragma unroll
    for (int u=1;u<16;u++) m2 = fmaxf(m2, v[u]);
    m2 = fmaxf(m2, __shfl_xor(m2, 1));  m2 = fmaxf(m2, __shfl_xor(m2, 2));
    m2 = fmaxf(m2, __shfl_xor(m2, 4));  m2 = fmaxf(m2, __shfl_xor(m2, 8));
    m2 = fmaxf(m2, __shfl_xor(m2, 16));
    float l2 = 0.f;
    #pragma unroll
    for (int u=0;u<16;u++) l2 += expf(v[u]-m2);
    l2 += __shfl_xor(l2, 1); l2 += __shfl_xor(l2, 2); l2 += __shfl_xor(l2, 4);
    l2 += __shfl_xor(l2, 8); l2 += __shfl_xor(l2, 16);
    float ls2 = m2 + logf(l2);
    float e[16];
    #pragma unroll
    for (int u=0;u<16;u++) e[u] = expf(v[u]-m2) / l2;
    #pragma unroll
    for (int ch=0; ch<4; ch++){
      float4 w4 = {e[ch*4], e[ch*4+1], e[ch*4+2], e[ch*4+3]};
      *(float4*)&out1[ob + ch*128] = w4;
    }
    // save per-row logsumexp for the DP kernel (log_soft = out0 - ls2)
    if (s_thr == 0) lse2[(size_t)b*TT2 + t] = ls2;
    // zero out2 (attn_hard) here so the serial DP kernel doesn't have to
    float4 z4 = {0.f, 0.f, 0.f, 0.f};
    #pragma unroll
    for (int ch=0; ch<4; ch++)
      *(float4*)&out2[ob + ch*128] = z4;
  }
}

// ---------------- MAS DP + backtrack. One wave per batch. ----------------
__device__ __forceinline__ void load8(const float* p, float* dst){
  float4 a = *(const float4*)p; float4 b = *(const float4*)(p+4);
  dst[0]=a.x; dst[1]=a.y; dst[2]=a.z; dst[3]=a.w;
  dst[4]=b.x; dst[5]=b.y; dst[6]=b.z; dst[7]=b.w;
}

#define DPD 16

// launch_bounds(64,1): allow the full VGPR budget so buf[16][8] stays live
// (at the default budget the scheduler sank the prefetch loads to their uses
//  -> ~700 cyc/row latency-bound; counters showed VGPR_Count=100 < 128-reg buf)
__global__ __launch_bounds__(64, 1) void dp_bt_kernel(
    const float* __restrict__ logprob,  // out0 (B,2048,512): attn = log_softmax + log prior
    const float* __restrict__ lse2,     // (B,2048): per-row logsumexp; log_soft = logprob - lse2
    float* __restrict__ hard,           // out2 (B,2048,512): pre-zeroed; scatter 1.0 on path
    const int* __restrict__ enc_len, const int* __restrict__ dec_len,
    unsigned char* __restrict__ takebits,
    float* __restrict__ dur)            // out3 (B,512)
{
  const int b = blockIdx.x;
  const int lane = threadIdx.x;
  const int el = enc_len[b];
  const int dl = dec_len[b];
  const float* rowbase = logprob + (size_t)b*TT2*TT1;
  const float* lseb = lse2 + (size_t)b*TT2;
  float* hardbase = hard + (size_t)b*TT2*TT1;
  unsigned char* tbb = takebits + (size_t)b*TT2*64;

  float logp[8];
  #pragma unroll
  for (int r=0;r<8;r++) logp[r] = (lane==0 && r==0) ? 0.f : NEGV;

  float buf[DPD][8];
  float lsev[DPD];
  #pragma unroll
  for (int d=0; d<DPD; d++){
    load8(rowbase + (size_t)d*TT1 + lane*8, buf[d]);
    lsev[d] = lseb[d];
  }

  for (int io = 0; io < TT2; io += DPD){
    #pragma unroll
    for (int d = 0; d < DPD; d++){
      const int i = io + d;
      const float lv = lsev[d];
      float la[8];
      #pragma unroll
      for (int r=0;r<8;r++){
        int j = lane*8 + r;
        bool valid = (j < el) && (i > 0 || j == 0);
        la[r] = valid ? (buf[d][r] - lv) : NEGV;
      }
      float bnd = __shfl_up(logp[7], 1);
      float sh0 = (lane == 0) ? NEGV : bnd;
      unsigned int tk = 0;
      float nl[8];
      { bool t_ = (lane > 0) && (sh0 >= logp[0]);
        tk |= t_ ? 1u : 0u;
        nl[0] = la[0] + (t_ ? sh0 : logp[0]); }
      #pragma unroll
      for (int r=1;r<8;r++){
        bool t_ = (logp[r-1] >= logp[r]);
        tk |= (t_ ? 1u : 0u) << r;
        nl[r] = la[r] + (t_ ? logp[r-1] : logp[r]);
      }
      #pragma unroll
      for (int r=0;r<8;r++) logp[r] = nl[r];
      tbb[(size_t)i*64 + lane] = (unsigned char)tk;
      if (i + DPD < TT2){
        load8(rowbase + (size_t)(i+DPD)*TT1 + lane*8, buf[d]);
        lsev[d] = lseb[i + DPD];
      }
    }
  }

  __threadfence();

  // backtrack
  int curr = el - 1;
  int dcount[8];
  #pragma unroll
  for (int r=0;r<8;r++) dcount[r] = 0;
  unsigned int tb[DPD];
  #pragma unroll
  for (int d=0; d<DPD; d++) tb[d] = tbb[(size_t)(TT2-1-d)*64 + lane];

  for (int io = 0; io < TT2; io += DPD){
    #pragma unroll
    for (int d=0; d<DPD; d++){
      const int i = TT2 - 1 - (io + d);
      bool active = i < dl;
      int owner = curr >> 3;
      if (active && lane == owner){
        hardbase[(size_t)i*TT1 + curr] = 1.0f;
      }
      #pragma unroll
      for (int r=0;r<8;r++)
        dcount[r] += (active && curr == lane*8 + r) ? 1 : 0;
      int sb = __shfl((int)tb[d], owner);
      int take = (sb >> (curr & 7)) & 1;
      if (active) curr -= take;
      int ni = i - DPD;
      if (ni >= 0) tb[d] = tbb[(size_t)ni*64 + lane];
    }
  }
  #pragma unroll
  for (int r=0;r<8;r++) dur[(size_t)b*TT1 + lane*8 + r] = (float)dcount[r];
}

extern "C" void kernel_launch(void* const* d_in, const int* in_sizes, int n_in,
                              void* d_out, int out_size, void* d_ws, size_t ws_size,
                              hipStream_t stream){
  const float* enc_in  = (const float*)d_in[0];
  const float* dec_in  = (const float*)d_in[1];
  const int*   enc_len = (const int*)d_in[2];
  const int*   dec_len = (const int*)d_in[3];
  // d_in[4] enc_mask: unused by reference
  const float* prior   = (const float*)d_in[5];
  const float* kw1 = (const float*)d_in[6];
  const float* kb1 = (const float*)d_in[7];
  const float* kw2 = (const float*)d_in[8];
  const float* kb2 = (const float*)d_in[9];
  const float* qw1 = (const float*)d_in[10];
  const float* qb1 = (const float*)d_in[11];
  const float* qw2 = (const float*)d_in[12];
  const float* qb2 = (const float*)d_in[13];
  const float* qw3 = (const float*)d_in[14];
  const float* qb3 = (const float*)d_in[15];

  float* out0 = (float*)d_out;                       // attn_logprob (B,1,2048,512)
  float* out1 = out0 + (size_t)BB*TT2*TT1;           // attn_soft
  float* out2 = out1 + (size_t)BB*TT2*TT1;           // attn_hard (zeroed by attn_kernel)
  float* out3 = out2 + (size_t)BB*TT2*TT1;           // attn_hard_dur (B,512)

  float* ws    = (float*)d_ws;
  float* k1buf = ws;                                  // 32*80*512
  float* kbuf  = k1buf + (size_t)BB*HH*TT1;           // 32*80*512
  float* qa    = kbuf  + (size_t)BB*HH*TT1;           // 32*80*2048
  float* qbuf2 = qa    + (size_t)BB*HH*TT2;           // 32*80*2048
  float* k2v   = qbuf2 + (size_t)BB*HH*TT2;           // 32*512
  float* lsebuf = k2v + (size_t)BB*TT1;               // 32*2048
  unsigned char* takebits = (unsigned char*)(lsebuf + (size_t)BB*TT2); // 32*2048*64 bytes

  conv_k1<<<dim3(8,BB),256,0,stream>>>(enc_in, kw1, kb1, k1buf);
  conv80<3,512,64,1><<<dim3(8,BB),256,0,stream>>>(k1buf, kw2, kb2, kbuf);
  k2_kernel<<<BB,256,0,stream>>>(kbuf, k2v);
  conv80<7,2048,128,2><<<dim3(16,BB),256,0,stream>>>(dec_in, qw1, qb1, qa);
  conv80<7,2048,128,2><<<dim3(16,BB),256,0,stream>>>(qa, qw2, qb2, qbuf2);
  conv80<7,2048,128,2><<<dim3(16,BB),256,0,stream>>>(qbuf2, qw3, qb3, qa);
  attn_kernel<<<dim3(64,BB),256,0,stream>>>(qa, kbuf, k2v, prior, out0, out1, out2, lsebuf);
  dp_bt_kernel<<<BB,64,0,stream>>>(out0, lsebuf, out2, enc_len, dec_len, takebits, out3);
}

// Round 2
// 1977.466 us; speedup vs baseline: 1.3287x; 1.3287x over previous
//
#include <hip/hip_runtime.h>
#include <math.h>

#define BB 32
#define TT1 512
#define TT2 2048
#define HH 80
#define DENC 512
#define NEGV -1000000000.0f
#define SLOPE_ 0.3f
#define TEMP_ 0.0005f

__device__ __forceinline__ float lrelu(float y){ return y >= 0.f ? y : SLOPE_*y; }

// ---------------- conv1: enc_in (B,512,512) -> (B,80,512), k=3 pad=1 ----------------
__global__ __launch_bounds__(256) void conv_k1(
    const float* __restrict__ x, const float* __restrict__ w,
    const float* __restrict__ bias, float* __restrict__ out)
{
  __shared__ float xs[128][66];
  const int b = blockIdx.y;
  const int t0 = blockIdx.x * 64;
  const float* xb = x + (size_t)b*DENC*TT1;
  const int tl = threadIdx.x & 63;
  const int og = __builtin_amdgcn_readfirstlane(threadIdx.x >> 6); // 0..3, 20 outs each
  float acc[20];
  #pragma unroll
  for (int i=0;i<20;i++) acc[i] = 0.f;
  for (int cc = 0; cc < 4; cc++){
    __syncthreads();
    for (int idx = threadIdx.x; idx < 128*66; idx += 256){
      int c = idx / 66, tt = idx - c*66;
      int t = t0 + tt - 1;
      xs[c][tt] = (t >= 0 && t < TT1) ? xb[(size_t)(cc*128 + c)*TT1 + t] : 0.f;
    }
    __syncthreads();
    for (int c = 0; c < 128; c++){
      float x0 = xs[c][tl], x1 = xs[c][tl+1], x2 = xs[c][tl+2];
      const int cg = cc*128 + c;
      #pragma unroll
      for (int oo=0;oo<20;oo++){
        const float* wp = w + (size_t)(og*20+oo)*1536 + cg*3;
        acc[oo] += wp[0]*x0 + wp[1]*x1 + wp[2]*x2;
      }
    }
  }
  #pragma unroll
  for (int oo=0;oo<20;oo++){
    int o = og*20+oo;
    float y = acc[oo] + bias[o];
    out[((size_t)b*HH + o)*TT1 + t0 + tl] = lrelu(y);
  }
}

// ---------------- generic 80->80 conv ----------------
template<int KS, int T, int TTILE, int TPW>
__global__ __launch_bounds__(256) void conv80(
    const float* __restrict__ x, const float* __restrict__ w,
    const float* __restrict__ bias, float* __restrict__ out)
{
  constexpr int PAD = (KS-1)/2;
  constexpr int XW = TTILE + KS - 1;
  __shared__ float xs[80][XW];
  const int b = blockIdx.y;
  const int t0 = blockIdx.x * TTILE;
  const float* xb = x + (size_t)b*80*T;
  for (int idx = threadIdx.x; idx < 80*XW; idx += 256){
    int c = idx / XW, tt = idx - c*XW;
    int t = t0 + tt - PAD;
    xs[c][tt] = (t >= 0 && t < T) ? xb[(size_t)c*T + t] : 0.f;
  }
  __syncthreads();
  const int tl = threadIdx.x & 63;
  const int og = __builtin_amdgcn_readfirstlane(threadIdx.x >> 6);
  const float* wb = w + (size_t)og*20*80*KS;
  float acc[TPW][20];
  #pragma unroll
  for (int i=0;i<TPW;i++)
    #pragma unroll
    for (int j=0;j<20;j++) acc[i][j] = 0.f;
  for (int c=0;c<80;c++){
    float xv[TPW + KS - 1];
    #pragma unroll
    for (int u=0;u<TPW+KS-1;u++) xv[u] = xs[c][tl*TPW + u];
    #pragma unroll
    for (int oo=0;oo<20;oo++){
      const float* wp = wb + (size_t)oo*80*KS + c*KS;
      #pragma unroll
      for (int dt=0; dt<KS; dt++){
        float wv = wp[dt];
        #pragma unroll
        for (int tt=0;tt<TPW;tt++)
          acc[tt][oo] += wv * xv[tt+dt];
      }
    }
  }
  #pragma unroll
  for (int oo=0;oo<20;oo++){
    int o = og*20 + oo;
    float bv = bias[o];
    if (TPW == 2){
      float2 y2;
      y2.x = lrelu(acc[0][oo] + bv);
      y2.y = lrelu(acc[1][oo] + bv);
      *(float2*)&out[((size_t)b*80 + o)*T + t0 + tl*2] = y2;
    } else {
      out[((size_t)b*80 + o)*T + t0 + tl] = lrelu(acc[0][oo] + bv);
    }
  }
}

// ---------------- k2 = sum_c k^2 ----------------
__global__ __launch_bounds__(256) void k2_kernel(const float* __restrict__ k, float* __restrict__ k2){
  int b = blockIdx.x;
  for (int s = threadIdx.x; s < TT1; s += 256){
    float a = 0.f;
    for (int c=0;c<80;c++){
      float v = k[((size_t)b*80 + c)*TT1 + s];
      a += v*v;
    }
    k2[b*TT1 + s] = a;
  }
}

// ---------------- attention: qk, two softmaxes, write out0/out1, zero out2, save lse2 ----------------
__global__ __launch_bounds__(256) void attn_kernel(
    const float* __restrict__ q,    // (B,80,2048)
    const float* __restrict__ k,    // (B,80,512)
    const float* __restrict__ k2g,  // (B,512)
    const float* __restrict__ prior,// (B,512,2048)
    float* __restrict__ out0, float* __restrict__ out1, float* __restrict__ out2,
    float* __restrict__ lse2)       // (B,2048): logsumexp of out0 rows
{
  const int b = blockIdx.y;
  const int t0 = blockIdx.x * 32;
  __shared__ float klds[80][128];
  __shared__ float qlds[80][32];
  __shared__ float q2lds[32];
  const int tid = threadIdx.x;
  const float* qb = q + (size_t)b*80*TT2;
  const float* kb = k + (size_t)b*80*TT1;
  for (int idx = tid; idx < 80*32; idx += 256){
    int c = idx >> 5, tt = idx & 31;
    qlds[c][tt] = qb[(size_t)c*TT2 + t0 + tt];
  }
  __syncthreads();
  if (tid < 32){
    float s = 0.f;
    for (int c = 0; c < 80; c++){ float v = qlds[c][tid]; s += v*v; }
    q2lds[tid] = s;
  }
  const int s_thr = tid & 31;   // 4 s each (per chunk)
  const int t_thr = tid >> 5;   // 4 t each
  float acc[4][16];
  #pragma unroll
  for (int i=0;i<4;i++)
    #pragma unroll
    for (int j=0;j<16;j++) acc[i][j] = 0.f;
  #pragma unroll
  for (int ch = 0; ch < 4; ch++){
    __syncthreads();
    for (int idx = tid; idx < 80*128; idx += 256){
      int c = idx >> 7, ss = idx & 127;
      klds[c][ss] = kb[(size_t)c*TT1 + ch*128 + ss];
    }
    __syncthreads();
    for (int c = 0; c < 80; c++){
      float4 kv = *(const float4*)&klds[c][s_thr<<2];
      float4 qv = *(const float4*)&qlds[c][t_thr<<2];
      float kx[4] = {kv.x,kv.y,kv.z,kv.w};
      float qx[4] = {qv.x,qv.y,qv.z,qv.w};
      #pragma unroll
      for (int tt=0;tt<4;tt++)
        #pragma unroll
        for (int jj=0;jj<4;jj++)
          acc[tt][ch*4+jj] += qx[tt]*kx[jj];
    }
  }
  // k2 for this thread's 16 s columns
  float k2l[16];
  #pragma unroll
  for (int ch=0; ch<4; ch++){
    float4 kk = *(const float4*)&k2g[(size_t)b*TT1 + ch*128 + (s_thr<<2)];
    k2l[ch*4+0]=kk.x; k2l[ch*4+1]=kk.y; k2l[ch*4+2]=kk.z; k2l[ch*4+3]=kk.w;
  }
  #pragma unroll
  for (int tt=0; tt<4; tt++){
    const int t = t0 + (t_thr<<2) + tt;
    const float q2t = q2lds[(t_thr<<2)+tt];
    float v[16];
    #pragma unroll
    for (int u=0;u<16;u++) v[u] = -TEMP_ * (q2t + k2l[u] - 2.f*acc[tt][u]);
    // prior loads (early issue)
    float pv[16];
    #pragma unroll
    for (int ch=0; ch<4; ch++)
      #pragma unroll
      for (int jj=0;jj<4;jj++){
        int s = ch*128 + (s_thr<<2) + jj;
        pv[ch*4+jj] = prior[((size_t)b*TT1 + s)*TT2 + t];
      }
    // pass 1: log_softmax over 512 (32-lane group reduce)
    float m = v[0];
    #pragma unroll
    for (int u=1;u<16;u++) m = fmaxf(m, v[u]);
    m = fmaxf(m, __shfl_xor(m, 1));  m = fmaxf(m, __shfl_xor(m, 2));
    m = fmaxf(m, __shfl_xor(m, 4));  m = fmaxf(m, __shfl_xor(m, 8));
    m = fmaxf(m, __shfl_xor(m, 16));
    float l = 0.f;
    #pragma unroll
    for (int u=0;u<16;u++) l += expf(v[u]-m);
    l += __shfl_xor(l, 1); l += __shfl_xor(l, 2); l += __shfl_xor(l, 4);
    l += __shfl_xor(l, 8); l += __shfl_xor(l, 16);
    float lse = m + logf(l);
    #pragma unroll
    for (int u=0;u<16;u++) v[u] = v[u] - lse + logf(pv[u] + 1e-8f);
    size_t ob = ((size_t)b*TT2 + t)*TT1 + (s_thr<<2);
    #pragma unroll
    for (int ch=0; ch<4; ch++){
      float4 w4 = {v[ch*4], v[ch*4+1], v[ch*4+2], v[ch*4+3]};
      *(float4*)&out0[ob + ch*128] = w4;
    }
    // pass 2: softmax of v
    float m2 = v[0];
    #pragma unroll
    for (int u=1;u<16;u++) m2 = fmaxf(m2, v[u]);
    m2 = fmaxf(m2, __shfl_xor(m2, 1));  m2 = fmaxf(m2, __shfl_xor(m2, 2));
    m2 = fmaxf(m2, __shfl_xor(m2, 4));  m2 = fmaxf(m2, __shfl_xor(m2, 8));
    m2 = fmaxf(m2, __shfl_xor(m2, 16));
    float l2 = 0.f;
    #pragma unroll
    for (int u=0;u<16;u++) l2 += expf(v[u]-m2);
    l2 += __shfl_xor(l2, 1); l2 += __shfl_xor(l2, 2); l2 += __shfl_xor(l2, 4);
    l2 += __shfl_xor(l2, 8); l2 += __shfl_xor(l2, 16);
    float ls2 = m2 + logf(l2);
    float e[16];
    #pragma unroll
    for (int u=0;u<16;u++) e[u] = expf(v[u]-m2) / l2;
    #pragma unroll
    for (int ch=0; ch<4; ch++){
      float4 w4 = {e[ch*4], e[ch*4+1], e[ch*4+2], e[ch*4+3]};
      *(float4*)&out1[ob + ch*128] = w4;
    }
    // save per-row logsumexp for the DP kernel (log_soft = out0 - ls2)
    if (s_thr == 0) lse2[(size_t)b*TT2 + t] = ls2;
    // zero out2 (attn_hard) here so the serial DP kernel doesn't have to
    float4 z4 = {0.f, 0.f, 0.f, 0.f};
    #pragma unroll
    for (int ch=0; ch<4; ch++)
      *(float4*)&out2[ob + ch*128] = z4;
  }
}

// ---------------- MAS DP + backtrack. One wave per batch. ----------------
__device__ __forceinline__ void load8(const float* p, float* dst){
  float4 a = *(const float4*)p; float4 b = *(const float4*)(p+4);
  dst[0]=a.x; dst[1]=a.y; dst[2]=a.z; dst[3]=a.w;
  dst[4]=b.x; dst[5]=b.y; dst[6]=b.z; dst[7]=b.w;
}

#define DPD 16

// One wave per batch. The 16-row register prefetch pipeline is PINNED by an
// asm memory fence at the end of each row body: loads for row i+16 must issue
// in row i's slot and stay live in VGPRs (round-1 counters showed the
// scheduler sinking them to their uses -> full mem latency per row).
// Take-bits live in LDS (128 KB) so the backtrack never touches global memory.
__global__ __launch_bounds__(64, 1) void dp_bt_kernel(
    const float* __restrict__ logprob,  // out0 (B,2048,512): log_softmax + log prior
    const float* __restrict__ lse2,     // (B,2048): log_soft = logprob - lse2
    float* __restrict__ hard,           // out2 (B,2048,512): pre-zeroed; scatter 1.0 on path
    const int* __restrict__ enc_len, const int* __restrict__ dec_len,
    float* __restrict__ dur)            // out3 (B,512)
{
  __shared__ unsigned char tkl[TT2*64];  // take bits: [row][lane], 128 KB
  const int b = blockIdx.x;
  const int lane = threadIdx.x;
  const int el = enc_len[b];
  const int dl = dec_len[b];
  const float* rowbase = logprob + (size_t)b*TT2*TT1;
  const float* lseb = lse2 + (size_t)b*TT2;
  float* hardbase = hard + (size_t)b*TT2*TT1;

  float logp[8];
  #pragma unroll
  for (int r=0;r<8;r++) logp[r] = (lane==0 && r==0) ? 0.f : NEGV;

  float buf[DPD][8];
  float lsev[DPD];
  #pragma unroll
  for (int d=0; d<DPD; d++){
    load8(rowbase + (size_t)d*TT1 + lane*8, buf[d]);
    lsev[d] = lseb[d];
  }

  for (int io = 0; io < TT2; io += DPD){
    #pragma unroll
    for (int d = 0; d < DPD; d++){
      const int i = io + d;
      const float lv = lsev[d];
      float la[8];
      #pragma unroll
      for (int r=0;r<8;r++){
        int j = lane*8 + r;
        bool valid = (j < el) && (i > 0 || j == 0);
        la[r] = valid ? (buf[d][r] - lv) : NEGV;
      }
      float bnd = __shfl_up(logp[7], 1);
      float sh0 = (lane == 0) ? NEGV : bnd;
      unsigned int tk = 0;
      float nl[8];
      { bool t_ = (lane > 0) && (sh0 >= logp[0]);
        tk |= t_ ? 1u : 0u;
        nl[0] = la[0] + (t_ ? sh0 : logp[0]); }
      #pragma unroll
      for (int r=1;r<8;r++){
        bool t_ = (logp[r-1] >= logp[r]);
        tk |= (t_ ? 1u : 0u) << r;
        nl[r] = la[r] + (t_ ? logp[r-1] : logp[r]);
      }
      #pragma unroll
      for (int r=0;r<8;r++) logp[r] = nl[r];
      tkl[i*64 + lane] = (unsigned char)tk;
      // pinned prefetch of row i+16. Overread past row 2047 lands in out1
      // (same d_out allocation) and is never consumed - safe.
      load8(rowbase + (size_t)(i + DPD)*TT1 + lane*8, buf[d]);
      int li = i + DPD; if (li > TT2-1) li = TT2-1;
      lsev[d] = lseb[li];
      asm volatile("" ::: "memory"); // anti-sink fence: pin this row's loads here
    }
  }

  __syncthreads();

  // backtrack: rows >= dl are no-ops in the reference (no store, curr frozen) -> skip
  int curr = el - 1;
  int dcount[8];
  #pragma unroll
  for (int r=0;r<8;r++) dcount[r] = 0;
  for (int i = dl - 1; i >= 0; --i){
    int owner = curr >> 3;
    if (lane == owner) hardbase[(size_t)i*TT1 + curr] = 1.0f;
    #pragma unroll
    for (int r=0;r<8;r++) dcount[r] += (curr == lane*8 + r) ? 1 : 0;
    unsigned int byte_ = tkl[i*64 + owner];   // uniform LDS broadcast read
    int take = (byte_ >> (curr & 7)) & 1;
    curr -= take;
  }
  #pragma unroll
  for (int r=0;r<8;r++) dur[(size_t)b*TT1 + lane*8 + r] = (float)dcount[r];
}

extern "C" void kernel_launch(void* const* d_in, const int* in_sizes, int n_in,
                              void* d_out, int out_size, void* d_ws, size_t ws_size,
                              hipStream_t stream){
  const float* enc_in  = (const float*)d_in[0];
  const float* dec_in  = (const float*)d_in[1];
  const int*   enc_len = (const int*)d_in[2];
  const int*   dec_len = (const int*)d_in[3];
  // d_in[4] enc_mask: unused by reference
  const float* prior   = (const float*)d_in[5];
  const float* kw1 = (const float*)d_in[6];
  const float* kb1 = (const float*)d_in[7];
  const float* kw2 = (const float*)d_in[8];
  const float* kb2 = (const float*)d_in[9];
  const float* qw1 = (const float*)d_in[10];
  const float* qb1 = (const float*)d_in[11];
  const float* qw2 = (const float*)d_in[12];
  const float* qb2 = (const float*)d_in[13];
  const float* qw3 = (const float*)d_in[14];
  const float* qb3 = (const float*)d_in[15];

  float* out0 = (float*)d_out;                       // attn_logprob (B,1,2048,512)
  float* out1 = out0 + (size_t)BB*TT2*TT1;           // attn_soft
  float* out2 = out1 + (size_t)BB*TT2*TT1;           // attn_hard (zeroed by attn_kernel)
  float* out3 = out2 + (size_t)BB*TT2*TT1;           // attn_hard_dur (B,512)

  float* ws    = (float*)d_ws;
  float* k1buf = ws;                                  // 32*80*512
  float* kbuf  = k1buf + (size_t)BB*HH*TT1;           // 32*80*512
  float* qa    = kbuf  + (size_t)BB*HH*TT1;           // 32*80*2048
  float* qbuf2 = qa    + (size_t)BB*HH*TT2;           // 32*80*2048
  float* k2v   = qbuf2 + (size_t)BB*HH*TT2;           // 32*512
  float* lsebuf = k2v + (size_t)BB*TT1;               // 32*2048

  conv_k1<<<dim3(8,BB),256,0,stream>>>(enc_in, kw1, kb1, k1buf);
  conv80<3,512,64,1><<<dim3(8,BB),256,0,stream>>>(k1buf, kw2, kb2, kbuf);
  k2_kernel<<<BB,256,0,stream>>>(kbuf, k2v);
  conv80<7,2048,128,2><<<dim3(16,BB),256,0,stream>>>(dec_in, qw1, qb1, qa);
  conv80<7,2048,128,2><<<dim3(16,BB),256,0,stream>>>(qa, qw2, qb2, qbuf2);
  conv80<7,2048,128,2><<<dim3(16,BB),256,0,stream>>>(qbuf2, qw3, qb3, qa);
  attn_kernel<<<dim3(64,BB),256,0,stream>>>(qa, kbuf, k2v, prior, out0, out1, out2, lsebuf);
  dp_bt_kernel<<<BB,64,0,stream>>>(out0, lsebuf, out2, enc_len, dec_len, out3);
}